// Round 5
// baseline (32.000 us; speedup 1.0000x reference)
//
#include <hip/hip_runtime.h>

// out[b,e,t] = sum_{s<=t} x[s]*(w0[s]*dv0^(t-s) + w1[t]*dv1^(t-s)) + bias[t]
//   P[t] = dv0*P[t-1] + x[t]*w0[t];  Q[t] = dv1*Q[t-1] + x[t]
//   out[t] = P[t] + w1[t]*Q[t] + bias[t]
// 4 rows per 256-thread block, processed SEQUENTIALLY with register double-
// buffering: row r+1's global loads are issued before row r's scan and stay
// in flight across the carry barrier (raw s_barrier + lgkmcnt-only drain --
// no vmcnt(0) drain like __syncthreads would emit). Per-row carry LDS slots
// avoid any second barrier. Fused epilogue, NT float4 stores.

#define S_LEN 2048
#define THREADS 256
#define RPB 4

typedef float f4 __attribute__((ext_vector_type(4)));

__global__ __launch_bounds__(THREADS, 4)
void crcl_kernel(const float* __restrict__ x,
                 const float* __restrict__ weight,
                 const float* __restrict__ bias,
                 const float* __restrict__ decay,
                 float* __restrict__ out,
                 int nrows)
{
    __shared__ float carry[RPB][2][4];   // [row][p/q][wave] -- no reuse, no WAR

    const int t    = (int)threadIdx.x;
    const int lane = t & 63;
    const int w    = t >> 6;
    const long row0 = (long)blockIdx.x * RPB;

    // ---- block-invariant shared arrays (held in registers) ----
    const f4* w04 = (const f4*)weight;            // weight[0][:]
    const f4* w14 = (const f4*)(weight + S_LEN);  // weight[1][:]
    const f4* b4  = (const f4*)bias;
    const f4 wa = w04[2 * t], wb = w04[2 * t + 1];
    const f4 va = w14[2 * t], vb = w14[2 * t + 1];
    const f4 ba = b4[2 * t],  bb = b4[2 * t + 1];

    const float dv0 = fminf(fmaxf(decay[0], 0.9f), 1.0f);
    const float dv1 = fminf(fmaxf(decay[1], 0.9f), 1.0f);

    float A8_0 = dv0 * dv0; A8_0 *= A8_0; A8_0 *= A8_0;   // dv0^8
    float A8_1 = dv1 * dv1; A8_1 *= A8_1; A8_1 *= A8_1;   // dv1^8
    float A512_0 = A8_0, A512_1 = A8_1;                   // dv^512
#pragma unroll
    for (int b = 0; b < 6; ++b) { A512_0 *= A512_0; A512_1 *= A512_1; }
    const float e8 = (float)(8 * lane);
    const float pwl_0 = exp2f(e8 * log2f(dv0));           // dv0^(8*lane)
    const float pwl_1 = exp2f(e8 * log2f(dv1));

    // ---- register double buffer for x; prologue loads row 0 ----
    f4 x0a, x0b, x1a, x1b;
    {
        long rr = row0; if (rr >= nrows) rr = nrows - 1;
        const f4* p = (const f4*)(x + rr * (long)S_LEN);
        x0a = p[2 * t]; x0b = p[2 * t + 1];
    }

#pragma unroll
    for (int r = 0; r < RPB; ++r) {
        // issue next row's loads into the opposite buffer (stay in flight
        // across the scan + raw barrier below)
        if (r + 1 < RPB) {
            long rn = row0 + r + 1; if (rn >= nrows) rn = nrows - 1;
            const f4* p = (const f4*)(x + rn * (long)S_LEN);
            if ((r & 1) == 0) { x1a = p[2 * t]; x1b = p[2 * t + 1]; }
            else              { x0a = p[2 * t]; x0b = p[2 * t + 1]; }
        }
        const f4 xA = (r & 1) ? x1a : x0a;   // r is compile-time (full unroll)
        const f4 xB = (r & 1) ? x1b : x0b;

        // ---- pass 1: per-thread segment totals ----
        float pc = 0.0f, qc = 0.0f;
#pragma unroll
        for (int j = 0; j < 4; ++j) {
            pc = fmaf(dv0, pc, xA[j] * wa[j]);
            qc = fmaf(dv1, qc, xA[j]);
        }
#pragma unroll
        for (int j = 0; j < 4; ++j) {
            pc = fmaf(dv0, pc, xB[j] * wb[j]);
            qc = fmaf(dv1, qc, xB[j]);
        }

        // ---- wave Kogge-Stone scan of segment carries (A = dv^8) ----
        float cp = pc, cq = qc, k0 = A8_0, k1 = A8_1;
#pragma unroll
        for (int d = 1; d < 64; d <<= 1) {
            const float up = __shfl_up(cp, (unsigned)d, 64);
            const float uq = __shfl_up(cq, (unsigned)d, 64);
            if (lane >= d) {
                cp = fmaf(k0, up, cp);
                cq = fmaf(k1, uq, cq);
            }
            k0 *= k0;
            k1 *= k1;
        }
        float cin_p = __shfl_up(cp, 1u, 64);
        float cin_q = __shfl_up(cq, 1u, 64);
        if (lane == 0) { cin_p = 0.0f; cin_q = 0.0f; }

        // ---- cross-wave exchange: lgkmcnt-only drain + raw barrier ----
        if (lane == 63) { carry[r][0][w] = cp; carry[r][1][w] = cq; }
        asm volatile("s_waitcnt lgkmcnt(0)" ::: "memory");
        __builtin_amdgcn_sched_barrier(0);
        __builtin_amdgcn_s_barrier();          // global loads stay in flight
        __builtin_amdgcn_sched_barrier(0);

        float cwp = 0.0f, cwq = 0.0f;
#pragma unroll
        for (int v = 0; v < 3; ++v) {
            if (v < w) {
                cwp = fmaf(cwp, A512_0, carry[r][0][v]);
                cwq = fmaf(cwq, A512_1, carry[r][1][v]);
            }
        }
        cin_p = fmaf(cwp, pwl_0, cin_p);
        cin_q = fmaf(cwq, pwl_1, cin_q);

        // ---- pass 2: recompute seeded with carry, fused epilogue ----
        float p2 = cin_p, q2 = cin_q;
        f4 ya, yb;
#pragma unroll
        for (int j = 0; j < 4; ++j) {
            p2 = fmaf(dv0, p2, xA[j] * wa[j]);
            q2 = fmaf(dv1, q2, xA[j]);
            ya[j] = fmaf(va[j], q2, p2) + ba[j];
        }
#pragma unroll
        for (int j = 0; j < 4; ++j) {
            p2 = fmaf(dv0, p2, xB[j] * wb[j]);
            q2 = fmaf(dv1, q2, xB[j]);
            yb[j] = fmaf(vb[j], q2, p2) + bb[j];
        }

        long rs = row0 + r; if (rs >= nrows) rs = nrows - 1;
        f4* o4 = (f4*)(out + rs * (long)S_LEN);
        __builtin_nontemporal_store(ya, &o4[2 * t]);
        __builtin_nontemporal_store(yb, &o4[2 * t + 1]);
    }
}

extern "C" void kernel_launch(void* const* d_in, const int* in_sizes, int n_in,
                              void* d_out, int out_size, void* d_ws, size_t ws_size,
                              hipStream_t stream) {
    const float* x      = (const float*)d_in[0];
    const float* weight = (const float*)d_in[1];
    const float* bias   = (const float*)d_in[2];
    const float* decay  = (const float*)d_in[3];
    float* out = (float*)d_out;

    const int nrows   = in_sizes[0] / S_LEN;      // B*E = 8192
    const int nblocks = (nrows + RPB - 1) / RPB;  // 2048
    hipLaunchKernelGGL(crcl_kernel, dim3(nblocks), dim3(THREADS), 0, stream,
                       x, weight, bias, decay, out, nrows);
}

// Round 6
// 26.220 us; speedup vs baseline: 1.2204x; 1.2204x over previous
//
#include <hip/hip_runtime.h>

// out[b,e,t] = sum_{s<=t} x[s]*(w0[s]*dv0^(t-s) + w1[t]*dv1^(t-s)) + bias[t]
//   P[t] = dv0*P[t-1] + x[t]*w0[t];  Q[t] = dv1*Q[t-1] + x[t]
//   out[t] = P[t] + w1[t]*Q[t] + bias[t]
// One row per 256-thread block. Thread t owns float4 segments sA=t and
// sB=256+t  => every global load/store instruction has UNIT 16B lane stride
// (1 L2 request per cacheline; the previous 2t/2t+1 layout had 32B lane
// stride = 2 requests per line on both read and write streams).
// Scan: 4-elem segment totals -> wave Kogge-Stone over 2 independent
// segment sequences (factor dv^4) -> 8 chunk totals combined via 64B LDS
// (factor dv^256, one barrier) -> fixup + fused epilogue.

#define S_LEN 2048
#define THREADS 256

typedef float f4 __attribute__((ext_vector_type(4)));

__global__ __launch_bounds__(THREADS, 8)
void crcl_kernel(const float* __restrict__ x,
                 const float* __restrict__ weight,
                 const float* __restrict__ bias,
                 const float* __restrict__ decay,
                 float* __restrict__ out)
{
    __shared__ float ctot[2][8];    // [p/q][chunk 0..7], chunk = 64 segments

    const int t    = (int)threadIdx.x;
    const int lane = t & 63;
    const int w    = t >> 6;
    const long row = (long)blockIdx.x;

    // ---- global loads: all unit-lane-stride float4, issued up front ----
    const f4* x4  = (const f4*)(x + row * (long)S_LEN);
    const f4* w04 = (const f4*)weight;            // weight[0][:]
    const f4* w14 = (const f4*)(weight + S_LEN);  // weight[1][:]
    const f4* b4  = (const f4*)bias;

    const int sA = t, sB = 256 + t;               // owned f4 segments
    const f4 xA = x4[sA],  xB = x4[sB];
    const f4 wA = w04[sA], wB = w04[sB];
    const f4 vA = w14[sA], vB = w14[sB];
    const f4 bA = b4[sA],  bB = b4[sB];

    const float dv0 = fminf(fmaxf(decay[0], 0.9f), 1.0f);
    const float dv1 = fminf(fmaxf(decay[1], 0.9f), 1.0f);

    // powers: A4 = dv^4, A256 = dv^256, pwl = dv^(4*lane)
    float A4_0 = dv0 * dv0; A4_0 *= A4_0;
    float A4_1 = dv1 * dv1; A4_1 *= A4_1;
    float A256_0 = A4_0, A256_1 = A4_1;
#pragma unroll
    for (int b = 0; b < 6; ++b) { A256_0 *= A256_0; A256_1 *= A256_1; }
    const float e4 = (float)(4 * lane);
    const float pw0l = exp2f(e4 * log2f(dv0));
    const float pw1l = exp2f(e4 * log2f(dv1));

    // ---- pass 1: per-segment totals (4-fma chains, A/B independent) ----
    float TAp = 0.0f, TAq = 0.0f, TBp = 0.0f, TBq = 0.0f;
#pragma unroll
    for (int j = 0; j < 4; ++j) {
        TAp = fmaf(dv0, TAp, xA[j] * wA[j]);
        TAq = fmaf(dv1, TAq, xA[j]);
        TBp = fmaf(dv0, TBp, xB[j] * wB[j]);
        TBq = fmaf(dv1, TBq, xB[j]);
    }

    // ---- wave Kogge-Stone over lanes, factor A4; A and B independent ----
    float sAp = TAp, sAq = TAq, sBp = TBp, sBq = TBq;
    float k0 = A4_0, k1 = A4_1;
#pragma unroll
    for (int d = 1; d < 64; d <<= 1) {
        const float uAp = __shfl_up(sAp, (unsigned)d, 64);
        const float uAq = __shfl_up(sAq, (unsigned)d, 64);
        const float uBp = __shfl_up(sBp, (unsigned)d, 64);
        const float uBq = __shfl_up(sBq, (unsigned)d, 64);
        if (lane >= d) {
            sAp = fmaf(k0, uAp, sAp);
            sAq = fmaf(k1, uAq, sAq);
            sBp = fmaf(k0, uBp, sBp);
            sBq = fmaf(k1, uBq, sBq);
        }
        k0 *= k0;
        k1 *= k1;
    }
    // exclusive within-chunk prefixes
    float eAp = __shfl_up(sAp, 1u, 64);
    float eAq = __shfl_up(sAq, 1u, 64);
    float eBp = __shfl_up(sBp, 1u, 64);
    float eBq = __shfl_up(sBq, 1u, 64);
    if (lane == 0) { eAp = eAq = eBp = eBq = 0.0f; }

    // ---- chunk totals -> LDS (chunk w from A, chunk 4+w from B) ----
    if (lane == 63) {
        ctot[0][w]     = sAp;  ctot[1][w]     = sAq;
        ctot[0][4 + w] = sBp;  ctot[1][4 + w] = sBq;
    }
    __syncthreads();

    // ---- chunk carry-in: V_c = sum_{d<c} U_d * A256^(c-1-d) ----
    float GAp = 0.0f, GAq = 0.0f;                 // carry into chunk w
#pragma unroll
    for (int d = 0; d < 3; ++d) {
        if (d < w) {
            GAp = fmaf(A256_0, GAp, ctot[0][d]);
            GAq = fmaf(A256_1, GAq, ctot[1][d]);
        }
    }
    float GBp = 0.0f, GBq = 0.0f;                 // carry into chunk 4+w
#pragma unroll
    for (int d = 0; d < 7; ++d) {
        if (d < 4 + w) {
            GBp = fmaf(A256_0, GBp, ctot[0][d]);
            GBq = fmaf(A256_1, GBq, ctot[1][d]);
        }
    }

    // carry into segment = G * dv^(4*lane) + exclusive-wave-prefix
    const float cinAp = fmaf(GAp, pw0l, eAp);
    const float cinAq = fmaf(GAq, pw1l, eAq);
    const float cinBp = fmaf(GBp, pw0l, eBp);
    const float cinBq = fmaf(GBq, pw1l, eBq);

    // ---- pass 2: recompute seeded with carry, fused epilogue ----
    f4 yA, yB;
    {
        float p = cinAp, q = cinAq;
#pragma unroll
        for (int j = 0; j < 4; ++j) {
            p = fmaf(dv0, p, xA[j] * wA[j]);
            q = fmaf(dv1, q, xA[j]);
            yA[j] = fmaf(vA[j], q, p) + bA[j];
        }
    }
    {
        float p = cinBp, q = cinBq;
#pragma unroll
        for (int j = 0; j < 4; ++j) {
            p = fmaf(dv0, p, xB[j] * wB[j]);
            q = fmaf(dv1, q, xB[j]);
            yB[j] = fmaf(vB[j], q, p) + bB[j];
        }
    }

    f4* o4 = (f4*)(out + row * (long)S_LEN);
    o4[sA] = yA;        // unit 16B lane stride: 1 L2 request per line
    o4[sB] = yB;
}

extern "C" void kernel_launch(void* const* d_in, const int* in_sizes, int n_in,
                              void* d_out, int out_size, void* d_ws, size_t ws_size,
                              hipStream_t stream) {
    const float* x      = (const float*)d_in[0];
    const float* weight = (const float*)d_in[1];
    const float* bias   = (const float*)d_in[2];
    const float* decay  = (const float*)d_in[3];
    float* out = (float*)d_out;

    const int nrows = in_sizes[0] / S_LEN;   // B*E = 8192 rows, one block each
    hipLaunchKernelGGL(crcl_kernel, dim3(nrows), dim3(THREADS), 0, stream,
                       x, weight, bias, decay, out);
}